// Round 7
// baseline (337.775 us; speedup 1.0000x reference)
//
#include <hip/hip_runtime.h>
#include <math.h>

// BridgeNodes R7: full-grid write-only blocks + half-K staging.
//  - dot(x,y) is bitwise-symmetric under operand swap, so block (bm,bn)
//    computes A=tile bm, B=tile bn and writes ONLY tile (bn,bm) via the
//    coalesced float4 store path (the R6 "mirror" path). Every output tile is
//    written exactly once by its transpose partner. No triangular decode.
//  - A/B staged in two 64-k halves: 32 KB LDS -> 4 blocks/CU (was 64 KB/2).
//  - bf16 MFMA + threshold-band exact-fixup numerics unchanged (R5/R6-proven).

constexpr int GROUPS = 4;
constexpr int N = 4096;
constexpr int F = 128;
constexpr int BT = 128;
constexpr int TILES = N / BT;                    // 32
constexpr float THRESH = 0.6f;
constexpr float LOGIT = 0.405465108f;            // ln(1.5)
constexpr float BAND = 0.006f;                   // >> max bf16 dot error

constexpr size_t H_OFF_SHORTS = 8;               // counter occupies 16 B of ws
constexpr size_t H_ELEMS = (size_t)GROUPS * N * F;

using short8 = __attribute__((ext_vector_type(8))) short;
using f32x4  = __attribute__((ext_vector_type(4))) float;

__device__ __forceinline__ short f2bf_rne(float x) {
    unsigned u = __float_as_uint(x);
    return (short)((u + 0x7FFFu + ((u >> 16) & 1u)) >> 16);
}

__global__ void split_kernel(const float* __restrict__ in, short* __restrict__ h,
                             unsigned* __restrict__ cnt) {
    const int i = blockIdx.x * 256 + threadIdx.x;
    if (i == 0) *cnt = 0;                        // ws is re-poisoned each launch
    if (i < (int)H_ELEMS) h[i] = f2bf_rne(in[i]);
}

#define GLL16(gp, lp)                                                        \
    __builtin_amdgcn_global_load_lds(                                        \
        (const __attribute__((address_space(1))) void*)(gp),                 \
        (__attribute__((address_space(3))) void*)(lp), 16, 0, 0)

__global__ __launch_bounds__(256, 4)
void bridge_mfma_kernel(const short* __restrict__ W, float* __restrict__ out,
                        unsigned* __restrict__ cnt, unsigned* __restrict__ list,
                        unsigned cap) {
    __shared__ alignas(16) short ldsA[BT * 64];  // 16 KB (half-K)
    __shared__ alignas(16) short ldsB[BT * 64];  // 16 KB

    const int g  = blockIdx.y;
    const int bm = blockIdx.x >> 5;              // A tile (rows we dot FROM)
    const int bn = blockIdx.x & 31;              // B tile (rows we dot AGAINST)

    const int tid  = threadIdx.x;
    const int lane = tid & 63;
    const int wv   = tid >> 6;
    const int lm   = lane & 15;
    const int q    = lane >> 4;
    const int R    = (wv & 1) * 64;              // A quadrant
    const int C    = (wv >> 1) * 64;             // B quadrant

    const short* baseA = W + ((size_t)g * N + bm * BT) * F;
    const short* baseB = W + ((size_t)g * N + bn * BT) * F;

    // staging ids: 1024 granules (16 B) per matrix per half; 4 per thread
    f32x4 acc[4][4] = {};

#pragma unroll
    for (int kh = 0; kh < 2; ++kh) {             // two 64-k halves
        if (kh) __syncthreads();                 // prior half's frags consumed
        const int ko = kh * 64;
#pragma unroll
        for (int it = 0; it < 4; ++it) {
            const int g0 = tid + 256 * it;       // granule 0..1023
            const int r  = g0 >> 3;              // row 0..127
            const int o  = g0 & 7;               // octet slot 0..7
            const int so = o ^ (r & 7);          // XOR swizzle (conflict-free)
            GLL16(baseA + (size_t)r * F + ko + so * 8, &ldsA[g0 * 8]);
            GLL16(baseB + (size_t)r * F + ko + so * 8, &ldsB[g0 * 8]);
        }
        __syncthreads();                         // drains vmcnt before barrier

#pragma unroll
        for (int kcl = 0; kcl < 2; ++kcl) {      // two K=32 MFMA steps per half
            const int oc = kcl * 4 + q;          // my octet within the half
            short8 af[4], bf[4];
#pragma unroll
            for (int i = 0; i < 4; ++i) {
                const int row = R + i * 16 + lm; // row&7 == lm&7
                af[i] = *(const short8*)(ldsA + row * 64 + ((oc ^ (lm & 7)) * 8));
            }
#pragma unroll
            for (int j = 0; j < 4; ++j) {
                const int row = C + j * 16 + lm;
                bf[j] = *(const short8*)(ldsB + row * 64 + ((oc ^ (lm & 7)) * 8));
            }
#pragma unroll
            for (int i = 0; i < 4; ++i)
#pragma unroll
                for (int j = 0; j < 4; ++j)
                    acc[i][j] = __builtin_amdgcn_mfma_f32_16x16x32_bf16(
                        af[i], bf[j], acc[i][j], 0, 0, 0);
        }
    }

    // LDS frags consumed -> reuse ldsA head as block flag counters
    __syncthreads();
    unsigned* sc = (unsigned*)ldsA;              // sc[0]=blkCnt, sc[1]=blkBase
    if (tid == 0) sc[0] = 0;
    __syncthreads();

    // ---- epilogue per j: sigmoid + threshold + band flags, float4 store ----
    // acc[i][j][r] = dot(A-row bm*BT+R+i*16+q*4+r, B-row bn*BT+C+j*16+lm).
    // Store at out[(B-row)][(A-row)]  (dot symmetric; covers every tile once).
    const size_t outg = (size_t)g * N * N;
    unsigned local[8];
    int nf = 0;
#pragma unroll
    for (int j = 0; j < 4; ++j) {
        const unsigned orow = bn * BT + C + j * 16 + lm;
        float* o = out + outg + (size_t)orow * N + bm * BT + R;
        float v[4][4];
#pragma unroll
        for (int i = 0; i < 4; ++i)
#pragma unroll
            for (int r = 0; r < 4; ++r) {
                const float x = acc[i][j][r];
                const float e = __expf(-x);
                const float s = __builtin_amdgcn_rcpf(1.0f + e);
                v[i][r] = (s < THRESH) ? 0.0f : s;
                if (fabsf(x - LOGIT) < BAND) {
                    const unsigned ocol = bm * BT + R + i * 16 + q * 4 + r;
                    const unsigned enc = ((unsigned)g << 24) | (orow << 12) | ocol;
                    if (nf < 8) local[nf++] = enc;
                    else {                       // statistically never
                        const unsigned idx = atomicAdd(cnt, 1u);
                        if (idx < cap) list[idx] = enc;
                    }
                }
            }
#pragma unroll
        for (int i = 0; i < 4; ++i) {
            float4 t = {v[i][0], v[i][1], v[i][2], v[i][3]};
            *(float4*)(o + i * 16 + q * 4) = t;
        }
    }

    // ---- block-aggregated flag publication: ONE global atomic per block ----
    __syncthreads();
    unsigned myoff = 0;
    if (nf) myoff = atomicAdd(&sc[0], (unsigned)nf);
    __syncthreads();
    if (tid == 0) sc[1] = sc[0] ? atomicAdd(cnt, sc[0]) : 0u;
    __syncthreads();
    if (nf) {
        const unsigned base = sc[1] + myoff;
        for (int k = 0; k < nf; ++k)
            if (base + k < cap) list[base + k] = local[k];
    }
}

// ---- exact recompute of flagged entries: sequential fp32 fmaf + expf ----
__global__ void fixup_kernel(const float* __restrict__ nodes, float* __restrict__ out,
                             const unsigned* __restrict__ cnt,
                             const unsigned* __restrict__ list, unsigned cap) {
    unsigned n = *cnt;
    if (n > cap) n = cap;
    const unsigned stride = gridDim.x * blockDim.x;
    for (unsigned idx = blockIdx.x * blockDim.x + threadIdx.x; idx < n; idx += stride) {
        const unsigned p = list[idx];
        const unsigned g = p >> 24, row = (p >> 12) & 0xFFF, col = p & 0xFFF;
        const float* a = nodes + ((size_t)g * N + row) * F;
        const float* b = nodes + ((size_t)g * N + col) * F;
        float acc = 0.0f;
        for (int k = 0; k < F; ++k)              // sequential ascending-k == np
            acc = fmaf(a[k], b[k], acc);
        const float s = 1.0f / (1.0f + expf(-acc));
        const float v = (s < THRESH) ? 0.0f : s;
        out[(size_t)g * N * N + (size_t)row * N + col] = v;
        out[(size_t)g * N * N + (size_t)col * N + row] = v;
    }
}

extern "C" void kernel_launch(void* const* d_in, const int* in_sizes, int n_in,
                              void* d_out, int out_size, void* d_ws, size_t ws_size,
                              hipStream_t stream) {
    const float* nodes = (const float*)d_in[0];
    float* out = (float*)d_out;

    unsigned* cnt = (unsigned*)d_ws;
    short* h = (short*)d_ws + H_OFF_SHORTS;
    const size_t list_off_bytes = 16 + H_ELEMS * sizeof(short);
    unsigned* list = (unsigned*)((char*)d_ws + list_off_bytes);
    const size_t cap_sz = (ws_size > list_off_bytes + 16)
                              ? (ws_size - list_off_bytes) / sizeof(unsigned) : 0;
    const unsigned cap = (unsigned)(cap_sz > (1u << 22) ? (1u << 22) : cap_sz);

    split_kernel<<<(int)((H_ELEMS + 255) / 256), 256, 0, stream>>>(nodes, h, cnt);

    dim3 grid(TILES * TILES, GROUPS);            // 1024 x 4 = 4096 blocks
    bridge_mfma_kernel<<<grid, 256, 0, stream>>>(h, out, cnt, list, cap);

    fixup_kernel<<<512, 256, 0, stream>>>(nodes, out, cnt, list, cap);
}